// Round 1
// baseline (3195.051 us; speedup 1.0000x reference)
//
#include <hip/hip_runtime.h>
#include <hip/hip_bf16.h>
#include <stdint.h>
#include <stddef.h>

// ---------------- problem dims ----------------
#define NB 16
#define NS 256
#define NH 512
#define NE 256
#define NV 32000
#define NM (NB*NS)        // 4096 flattened rows, m = b*256 + s
#define N3H 1536

typedef __attribute__((ext_vector_type(8))) short short8v;
typedef __attribute__((ext_vector_type(4))) float float4v;
typedef __attribute__((address_space(1))) const unsigned int gas_u32;
typedef __attribute__((address_space(3))) unsigned int las_u32;

static __device__ __forceinline__ unsigned short f2bf(float f) {
  __hip_bfloat16 h = __float2bfloat16(f);
  return *reinterpret_cast<unsigned short*>(&h);
}
static __device__ __forceinline__ float bf2f(unsigned short u) {
  union { unsigned int u; float f; } c;
  c.u = ((unsigned int)u) << 16;
  return c.f;
}

// ---------------- embedding gather + convert to bf16 ----------------
__global__ void gather_emb(const int* __restrict__ x, const float* __restrict__ E,
                           unsigned short* __restrict__ A) {
  int m = blockIdx.x * 4 + (threadIdx.x >> 6);
  int lane = threadIdx.x & 63;
  int t = x[m];
  float4 v = reinterpret_cast<const float4*>(E + (size_t)t * NE)[lane];
  ushort4 o = make_ushort4(f2bf(v.x), f2bf(v.y), f2bf(v.z), f2bf(v.w));
  reinterpret_cast<ushort4*>(A + (size_t)m * NE)[lane] = o;
}

// ---------------- tiled transpose, f32 in -> (bf16|f32) out ----------------
// out[c][r] = in[r][c].  grid = (C/32, R/32), block = (32,8)
template<typename T>
__global__ void transpose_conv(const float* __restrict__ in, T* __restrict__ out,
                               int R, int C) {
  __shared__ float tile[32][33];
  int c0 = blockIdx.x * 32, r0 = blockIdx.y * 32;
  int tx = threadIdx.x, ty = threadIdx.y;
  #pragma unroll
  for (int i = 0; i < 32; i += 8)
    tile[ty + i][tx] = in[(size_t)(r0 + ty + i) * C + (c0 + tx)];
  __syncthreads();
  #pragma unroll
  for (int i = 0; i < 32; i += 8) {
    float v = tile[tx][ty + i];
    if constexpr (sizeof(T) == 2)
      out[(size_t)(c0 + ty + i) * R + (r0 + tx)] = (T)f2bf(v);
    else
      out[(size_t)(c0 + ty + i) * R + (r0 + tx)] = (T)v;
  }
}

// ---------------- bf16 MFMA GEMM: C[m][n] = sum_k A[m][k]*BT[n][k] + bias[n]
// A: M x K bf16 row-major; BT: N x K bf16 row-major; out f32 or bf16.
// 128x128 tile, BK=32, 4 waves (2x2), m97-style global_load_lds staging.
template<bool OUT_BF16>
__launch_bounds__(256)
__global__ void gemm_bt(const unsigned short* __restrict__ A,
                        const unsigned short* __restrict__ BT,
                        const float* __restrict__ bias,
                        void* __restrict__ out, int N, int K) {
  __shared__ unsigned short As[128 * 32];
  __shared__ unsigned short Bs[128 * 32];
  const int tid = threadIdx.x;
  const int lane = tid & 63, wave = tid >> 6;
  const int wr = wave >> 1, wc = wave & 1;
  const int m0 = blockIdx.y * 128, n0 = blockIdx.x * 128;
  const int lr = lane & 15, lg = lane >> 4;
  float4v acc[4][4] = {};

  for (int k0 = 0; k0 < K; k0 += 32) {
    const char* Ab = (const char*)A;
    const char* Bb = (const char*)BT;
    #pragma unroll
    for (int q = 0; q < 2; ++q) {
      int byteoff = q * 4096 + tid * 16;
      int r = byteoff >> 6, cb = byteoff & 63;
      const char* ga = Ab + ((size_t)(m0 + r) * K + k0) * 2 + cb;
      const char* gb = Bb + ((size_t)(n0 + r) * K + k0) * 2 + cb;
      char* la = (char*)As + q * 4096 + wave * 1024;   // wave-uniform LDS dest
      char* lb = (char*)Bs + q * 4096 + wave * 1024;
      __builtin_amdgcn_global_load_lds((gas_u32*)ga, (las_u32*)la, 16, 0, 0);
      __builtin_amdgcn_global_load_lds((gas_u32*)gb, (las_u32*)lb, 16, 0, 0);
    }
    __syncthreads();
    short8v a[4], b[4];
    #pragma unroll
    for (int i = 0; i < 4; ++i)
      a[i] = *(const short8v*)((const char*)As + (wr * 64 + i * 16 + lr) * 64 + lg * 16);
    #pragma unroll
    for (int j = 0; j < 4; ++j)
      b[j] = *(const short8v*)((const char*)Bs + (wc * 64 + j * 16 + lr) * 64 + lg * 16);
    #pragma unroll
    for (int i = 0; i < 4; ++i) {
      #pragma unroll
      for (int j = 0; j < 4; ++j)
        acc[i][j] = __builtin_amdgcn_mfma_f32_16x16x32_bf16(a[i], b[j], acc[i][j], 0, 0, 0);
    }
    __syncthreads();
  }
  // epilogue: C/D layout col = lane&15, row = (lane>>4)*4 + reg  [m89 verified]
  #pragma unroll
  for (int i = 0; i < 4; ++i) {
    int row = m0 + wr * 64 + i * 16 + lg * 4;
    #pragma unroll
    for (int j = 0; j < 4; ++j) {
      int col = n0 + wc * 64 + j * 16 + lr;
      float bv = bias[col];
      #pragma unroll
      for (int r = 0; r < 4; ++r) {
        float v = acc[i][j][r] + bv;
        if constexpr (OUT_BF16)
          ((unsigned short*)out)[(size_t)(row + r) * N + col] = f2bf(v);
        else
          ((float*)out)[(size_t)(row + r) * N + col] = v;
      }
    }
  }
}

// ---------------- persistent GRU ----------------
// 64 WGs x 384 threads. WG w owns h-dims [8w, 8w+8) -> 24 U columns (3 gates x 8)
// resident in LDS (bf16). Per step: distributed matvec rec = h @ U, gate, write
// h slice to step-indexed exchange buffer, release flag; poll all 64 flags.
__launch_bounds__(384, 1)
__global__ void gru_kernel(const unsigned short* __restrict__ xw,   // [4096][1536] bf16
                           const float* __restrict__ UT,            // [1536][512] f32
                           const float* __restrict__ bvec,          // b[2][1536]
                           unsigned short* __restrict__ Hall,       // [4096][512] bf16
                           unsigned int* __restrict__ Hex,          // [257][16][256] packed 2xbf16
                           unsigned int* __restrict__ flags) {      // [257][64], memset 0 per call
  const int w = blockIdx.x, tid = threadIdx.x;
  const int d0 = w * 8;
  __shared__ unsigned short h_lds[16 * 512];   // 16KB
  __shared__ unsigned short U_lds[24 * 512];   // 24KB
  __shared__ float red[192 * 16];              // 12KB

  // stage U columns (bf16) once; row c of U_lds = U column (c/8)*512 + d0 + (c%8)
  for (int idx = tid; idx < 24 * 128; idx += 384) {
    int c = idx >> 7, q = idx & 127;
    int ucol = (c >> 3) * 512 + d0 + (c & 7);
    float4 v = reinterpret_cast<const float4*>(UT + (size_t)ucol * 512)[q];
    ushort4 u = make_ushort4(f2bf(v.x), f2bf(v.y), f2bf(v.z), f2bf(v.w));
    *reinterpret_cast<ushort4*>(&U_lds[c * 512 + q * 4]) = u;
  }
  for (int idx = tid; idx < 1024; idx += 384)
    reinterpret_cast<uint4*>(h_lds)[idx] = make_uint4(0, 0, 0, 0);

  // gating threads (tid < 64): thread -> (batch gb, dim-pair gdp)
  float h0 = 0.f, h1 = 0.f;
  float bz0 = 0, bz1 = 0, br0 = 0, br1 = 0, bh0 = 0, bh1 = 0;
  int gb = 0, gdp = 0;
  if (tid < 64) {
    gb = tid >> 2; gdp = tid & 3;
    const float* brec = bvec + 1536;
    bz0 = brec[0 * 512 + d0 + gdp * 2]; bz1 = brec[0 * 512 + d0 + gdp * 2 + 1];
    br0 = brec[1 * 512 + d0 + gdp * 2]; br1 = brec[1 * 512 + d0 + gdp * 2 + 1];
    bh0 = brec[2 * 512 + d0 + gdp * 2]; bh1 = brec[2 * 512 + d0 + gdp * 2 + 1];
  }
  // matvec thread mapping: tid = b4*96 + c4*16 + ks  (4 batches x 4 cols x k-chunk)
  const int ks = tid & 15, c4 = (tid >> 4) % 6, b4 = tid / 96;
  __syncthreads();

  for (int s = 0; s < 256; ++s) {
    if (s > 0) {
      if (tid < 64) {
        while (__hip_atomic_load(&flags[s * 64 + tid], __ATOMIC_ACQUIRE,
                                 __HIP_MEMORY_SCOPE_AGENT) == 0u)
          __builtin_amdgcn_s_sleep(1);
      }
      __syncthreads();
      for (int idx = tid; idx < 4096; idx += 384) {
        unsigned int v = __hip_atomic_load(&Hex[(size_t)s * 4096 + idx],
                                           __ATOMIC_RELAXED, __HIP_MEMORY_SCOPE_AGENT);
        *reinterpret_cast<unsigned int*>(&h_lds[idx * 2]) = v;
      }
      __syncthreads();
    }
    // distributed matvec: acc[i][j] = sum_k h[b4*4+i][k] * U_lds[c4*4+j][k]
    // (k octets interleaved by ks to stay at structural LDS bank rate)
    float acc[4][4] = {};
    #pragma unroll
    for (int it = 0; it < 4; ++it) {
      int o = it * 16 + ks;
      short8v hv[4], uv[4];
      #pragma unroll
      for (int i = 0; i < 4; ++i) hv[i] = *(const short8v*)&h_lds[(b4 * 4 + i) * 512 + o * 8];
      #pragma unroll
      for (int j = 0; j < 4; ++j) uv[j] = *(const short8v*)&U_lds[(c4 * 4 + j) * 512 + o * 8];
      #pragma unroll
      for (int i = 0; i < 4; ++i) {
        #pragma unroll
        for (int j = 0; j < 4; ++j) {
          #pragma unroll
          for (int e = 0; e < 8; ++e)
            acc[i][j] += bf2f((unsigned short)hv[i][e]) * bf2f((unsigned short)uv[j][e]);
        }
      }
    }
    // pairwise shfl reduce (ks, ks+8), then 8 partials per dot in LDS
    #pragma unroll
    for (int i = 0; i < 4; ++i) {
      #pragma unroll
      for (int j = 0; j < 4; ++j) {
        float v = acc[i][j] + __shfl_xor(acc[i][j], 8, 64);
        if (ks < 8) red[(b4 * 48 + c4 * 8 + ks) * 16 + i * 4 + j] = v;
      }
    }
    __syncthreads();
    if (tid < 64) {
      float rec[2][3];
      #pragma unroll
      for (int u = 0; u < 2; ++u) {
        #pragma unroll
        for (int g = 0; g < 3; ++g) {
          int c = g * 8 + gdp * 2 + u;
          int c4r = c >> 2, jr = c & 3, b4r = gb >> 2, ir = gb & 3;
          float sum = 0.f;
          #pragma unroll
          for (int k2 = 0; k2 < 8; ++k2)
            sum += red[(b4r * 48 + c4r * 8 + k2) * 16 + ir * 4 + jr];
          rec[u][g] = sum;
        }
      }
      const unsigned short* xp = xw + (size_t)(gb * 256 + s) * 1536 + d0 + gdp * 2;
      float xz0 = bf2f(xp[0]),    xz1 = bf2f(xp[1]);
      float xr0 = bf2f(xp[512]),  xr1 = bf2f(xp[513]);
      float xh0 = bf2f(xp[1024]), xh1 = bf2f(xp[1025]);
      float z0 = 1.f / (1.f + __expf(-(xz0 + rec[0][0] + bz0)));
      float z1 = 1.f / (1.f + __expf(-(xz1 + rec[1][0] + bz1)));
      float r0 = 1.f / (1.f + __expf(-(xr0 + rec[0][1] + br0)));
      float r1 = 1.f / (1.f + __expf(-(xr1 + rec[1][1] + br1)));
      float hh0 = tanhf(xh0 + r0 * (rec[0][2] + bh0));
      float hh1 = tanhf(xh1 + r1 * (rec[1][2] + bh1));
      h0 = z0 * h0 + (1.f - z0) * hh0;
      h1 = z1 * h1 + (1.f - z1) * hh1;
      unsigned int pack = (unsigned int)f2bf(h0) | ((unsigned int)f2bf(h1) << 16);
      __hip_atomic_store(&Hex[(size_t)(s + 1) * 4096 + gb * 256 + (d0 >> 1) + gdp], pack,
                         __ATOMIC_RELAXED, __HIP_MEMORY_SCOPE_AGENT);
      *reinterpret_cast<unsigned int*>(&Hall[((size_t)(gb * 256 + s)) * 512 + d0 + gdp * 2]) = pack;
    }
    __syncthreads();   // drains vmcnt: slice stores complete at coherence point
    if (tid == 0) {
      __threadfence();
      __hip_atomic_store(&flags[(s + 1) * 64 + w], 1u,
                         __ATOMIC_RELEASE, __HIP_MEMORY_SCOPE_AGENT);
    }
  }
}

// ---------------- launch ----------------
extern "C" void kernel_launch(void* const* d_in, const int* in_sizes, int n_in,
                              void* d_out, int out_size, void* d_ws, size_t ws_size,
                              hipStream_t stream) {
  const int*   x  = (const int*)d_in[0];
  const float* E  = (const float*)d_in[1];
  const float* W  = (const float*)d_in[2];
  const float* U  = (const float*)d_in[3];
  const float* bv = (const float*)d_in[4];
  const float* Wd = (const float*)d_in[5];
  const float* bd = (const float*)d_in[6];
  float* out = (float*)d_out;

  char* ws = (char*)d_ws;
  size_t off = 0;
  auto alloc = [&](size_t bytes) -> void* {
    void* p = ws + off;
    off = (off + bytes + 255) & ~(size_t)255;
    return p;
  };
  unsigned short* Aemb = (unsigned short*)alloc((size_t)NM * NE * 2);       // 2 MB
  unsigned short* WT   = (unsigned short*)alloc((size_t)N3H * NE * 2);      // 0.75 MB
  float*          UT   = (float*)alloc((size_t)N3H * NH * 4);               // 3 MB
  unsigned short* xwb  = (unsigned short*)alloc((size_t)NM * N3H * 2);      // 12.6 MB
  unsigned short* WdT  = (unsigned short*)alloc((size_t)NV * NH * 2);       // 32.8 MB
  unsigned short* Hall = (unsigned short*)alloc((size_t)NM * NH * 2);       // 4.2 MB
  unsigned int*   Hex  = (unsigned int*)alloc((size_t)257 * 4096 * 4);      // 4.2 MB
  unsigned int*   flags= (unsigned int*)alloc((size_t)257 * 64 * 4);        // 66 KB

  hipMemsetAsync(flags, 0, 257 * 64 * 4, stream);

  gather_emb<<<NM / 4, 256, 0, stream>>>(x, E, Aemb);
  transpose_conv<unsigned short><<<dim3(N3H / 32, NE / 32), dim3(32, 8), 0, stream>>>(W,  WT,  NE, N3H);
  transpose_conv<unsigned short><<<dim3(NV / 32,  NH / 32), dim3(32, 8), 0, stream>>>(Wd, WdT, NH, NV);
  transpose_conv<float>         <<<dim3(N3H / 32, NH / 32), dim3(32, 8), 0, stream>>>(U,  UT,  NH, N3H);

  // xw = Aemb @ W + b[0]  (bf16 out)
  gemm_bt<true><<<dim3(N3H / 128, NM / 128), 256, 0, stream>>>(Aemb, WT, bv, xwb, N3H, NE);

  // GRU recurrence (persistent, 64 WGs)
  gru_kernel<<<64, 384, 0, stream>>>(xwb, UT, bv, Hall, Hex, flags);

  // logits = Hall @ Wd + bd  (f32 out)
  gemm_bt<false><<<dim3(NV / 128, NM / 128), 256, 0, stream>>>(Hall, WdT, bd, out, NV, NH);
}

// Round 2
// 1191.890 us; speedup vs baseline: 2.6807x; 2.6807x over previous
//
#include <hip/hip_runtime.h>
#include <hip/hip_bf16.h>
#include <stdint.h>
#include <stddef.h>

// ---------------- problem dims ----------------
#define NB 16
#define NS 256
#define NH 512
#define NE 256
#define NV 32000
#define NM (NB*NS)        // 4096 flattened rows, m = b*256 + s
#define N3H 1536

typedef __attribute__((ext_vector_type(8))) short short8v;
typedef __attribute__((ext_vector_type(4))) float float4v;
typedef __attribute__((address_space(1))) const unsigned int gas_u32;
typedef __attribute__((address_space(3))) unsigned int las_u32;

static __device__ __forceinline__ unsigned short f2bf(float f) {
  __hip_bfloat16 h = __float2bfloat16(f);
  return *reinterpret_cast<unsigned short*>(&h);
}
static __device__ __forceinline__ float bf2f(unsigned short u) {
  union { unsigned int u; float f; } c;
  c.u = ((unsigned int)u) << 16;
  return c.f;
}

// ---------------- embedding gather + convert to bf16 ----------------
__global__ void gather_emb(const int* __restrict__ x, const float* __restrict__ E,
                           unsigned short* __restrict__ A) {
  int m = blockIdx.x * 4 + (threadIdx.x >> 6);
  int lane = threadIdx.x & 63;
  int t = x[m];
  float4 v = reinterpret_cast<const float4*>(E + (size_t)t * NE)[lane];
  ushort4 o = make_ushort4(f2bf(v.x), f2bf(v.y), f2bf(v.z), f2bf(v.w));
  reinterpret_cast<ushort4*>(A + (size_t)m * NE)[lane] = o;
}

// ---------------- tiled transpose, f32 in -> (bf16|f32) out ----------------
template<typename T>
__global__ void transpose_conv(const float* __restrict__ in, T* __restrict__ out,
                               int R, int C) {
  __shared__ float tile[32][33];
  int c0 = blockIdx.x * 32, r0 = blockIdx.y * 32;
  int tx = threadIdx.x, ty = threadIdx.y;
  #pragma unroll
  for (int i = 0; i < 32; i += 8)
    tile[ty + i][tx] = in[(size_t)(r0 + ty + i) * C + (c0 + tx)];
  __syncthreads();
  #pragma unroll
  for (int i = 0; i < 32; i += 8) {
    float v = tile[tx][ty + i];
    if constexpr (sizeof(T) == 2)
      out[(size_t)(c0 + ty + i) * R + (r0 + tx)] = (T)f2bf(v);
    else
      out[(size_t)(c0 + ty + i) * R + (r0 + tx)] = (T)v;
  }
}

// ---------------- bf16 MFMA GEMM: C[m][n] = sum_k A[m][k]*BT[n][k] + bias[n]
template<bool OUT_BF16>
__launch_bounds__(256)
__global__ void gemm_bt(const unsigned short* __restrict__ A,
                        const unsigned short* __restrict__ BT,
                        const float* __restrict__ bias,
                        void* __restrict__ out, int N, int K) {
  __shared__ unsigned short As[128 * 32];
  __shared__ unsigned short Bs[128 * 32];
  const int tid = threadIdx.x;
  const int lane = tid & 63, wave = tid >> 6;
  const int wr = wave >> 1, wc = wave & 1;
  const int m0 = blockIdx.y * 128, n0 = blockIdx.x * 128;
  const int lr = lane & 15, lg = lane >> 4;
  float4v acc[4][4] = {};

  for (int k0 = 0; k0 < K; k0 += 32) {
    const char* Ab = (const char*)A;
    const char* Bb = (const char*)BT;
    #pragma unroll
    for (int q = 0; q < 2; ++q) {
      int byteoff = q * 4096 + tid * 16;
      int r = byteoff >> 6, cb = byteoff & 63;
      const char* ga = Ab + ((size_t)(m0 + r) * K + k0) * 2 + cb;
      const char* gb = Bb + ((size_t)(n0 + r) * K + k0) * 2 + cb;
      char* la = (char*)As + q * 4096 + wave * 1024;
      char* lb = (char*)Bs + q * 4096 + wave * 1024;
      __builtin_amdgcn_global_load_lds((gas_u32*)ga, (las_u32*)la, 16, 0, 0);
      __builtin_amdgcn_global_load_lds((gas_u32*)gb, (las_u32*)lb, 16, 0, 0);
    }
    __syncthreads();
    short8v a[4], b[4];
    #pragma unroll
    for (int i = 0; i < 4; ++i)
      a[i] = *(const short8v*)((const char*)As + (wr * 64 + i * 16 + lr) * 64 + lg * 16);
    #pragma unroll
    for (int j = 0; j < 4; ++j)
      b[j] = *(const short8v*)((const char*)Bs + (wc * 64 + j * 16 + lr) * 64 + lg * 16);
    #pragma unroll
    for (int i = 0; i < 4; ++i) {
      #pragma unroll
      for (int j = 0; j < 4; ++j)
        acc[i][j] = __builtin_amdgcn_mfma_f32_16x16x32_bf16(a[i], b[j], acc[i][j], 0, 0, 0);
    }
    __syncthreads();
  }
  #pragma unroll
  for (int i = 0; i < 4; ++i) {
    int row = m0 + wr * 64 + i * 16 + lg * 4;
    #pragma unroll
    for (int j = 0; j < 4; ++j) {
      int col = n0 + wc * 64 + j * 16 + lr;
      float bv = bias[col];
      #pragma unroll
      for (int r = 0; r < 4; ++r) {
        float v = acc[i][j][r] + bv;
        if constexpr (OUT_BF16)
          ((unsigned short*)out)[(size_t)(row + r) * N + col] = f2bf(v);
        else
          ((float*)out)[(size_t)(row + r) * N + col] = v;
      }
    }
  }
}

// ---------------- persistent GRU, data-as-flag exchange ----------------
// 16 WGs x 512 threads. WG w owns h-dims [32w, 32w+32) -> 96 U columns, held
// as B-fragments IN VGPRS (constant across steps). Per step:
//   poll Hex[s] words (sentinel 0xFFFFFFFF) -> h_lds (XOR-swizzled)
//   -> sync -> waves 0..5: rec = h @ U_slice via mfma 16x16x32 -> red
//   -> sync -> 256 gate threads: gates, h update, store Hex[s+1]/Hall.
#define SENT 0xFFFFFFFFu
__launch_bounds__(512, 1)
__global__ void gru_kernel(const unsigned short* __restrict__ xw,   // [4096][1536] bf16
                           const float* __restrict__ UT,            // [1536][512] f32
                           const float* __restrict__ bvec,          // b[2][1536]
                           unsigned short* __restrict__ Hall,       // [4096][512] bf16
                           unsigned int* __restrict__ Hex) {        // [257][4096] words, memset 0xFF
  const int w = blockIdx.x, tid = threadIdx.x;
  const int lane = tid & 63, wave = tid >> 6;
  const int lr = lane & 15, lg = lane >> 4;
  __shared__ unsigned short h_lds[16 * 512];   // 16KB, [batch][dim], swizzled
  __shared__ float red[16 * 97];               // rec staging, padded stride

  // ---- one-time: U slice -> VGPR B-fragments (waves 0..5) ----
  short8v Bf[16];
  if (wave < 6) {
    int c = wave * 16 + lr;                    // 0..95: col within slice
    int g = c >> 5, dloc = c & 31;
    const float* up = UT + (size_t)(g * 512 + 32 * w + dloc) * 512 + lg * 8;
    #pragma unroll
    for (int kk = 0; kk < 16; ++kk) {
      float4 v0 = *(const float4*)(up + kk * 32);
      float4 v1 = *(const float4*)(up + kk * 32 + 4);
      short8v t;
      t[0] = (short)f2bf(v0.x); t[1] = (short)f2bf(v0.y);
      t[2] = (short)f2bf(v0.z); t[3] = (short)f2bf(v0.w);
      t[4] = (short)f2bf(v1.x); t[5] = (short)f2bf(v1.y);
      t[6] = (short)f2bf(v1.z); t[7] = (short)f2bf(v1.w);
      Bf[kk] = t;
    }
  }
  // zero h_lds (h0 = 0)
  for (int idx = tid; idx < 1024; idx += 512)
    reinterpret_cast<uint4*>(h_lds)[idx] = make_uint4(0, 0, 0, 0);

  // ---- gate-thread constants (tid < 256): (batch gb, dim-pair dp) ----
  float h0 = 0.f, h1 = 0.f;
  float bz0 = 0, bz1 = 0, br0 = 0, br1 = 0, bh0 = 0, bh1 = 0;
  int gb = tid >> 4, dp = tid & 15;
  const unsigned int* xp = nullptr;
  if (tid < 256) {
    const float* brec = bvec + 1536;
    int d = 32 * w + 2 * dp;
    bz0 = brec[d];        bz1 = brec[d + 1];
    br0 = brec[512 + d];  br1 = brec[513 + d];
    bh0 = brec[1024 + d]; bh1 = brec[1025 + d];
    xp = (const unsigned int*)(xw + (size_t)(gb * 256) * 1536 + d);
  }
  __syncthreads();

  for (int s = 0; s < 256; ++s) {
    // prefetch xw for this step (hidden under poll)
    unsigned int xzw = 0, xrw = 0, xhw = 0;
    if (tid < 256) { xzw = xp[0]; xrw = xp[256]; xhw = xp[512]; xp += 768; }

    if (s > 0) {
      const unsigned int* src = Hex + (size_t)s * 4096;
      unsigned int vv[8];
      #pragma unroll
      for (int i = 0; i < 8; ++i)
        vv[i] = __hip_atomic_load(&src[tid + 512 * i], __ATOMIC_RELAXED,
                                  __HIP_MEMORY_SCOPE_AGENT);
      unsigned int pend = 0;
      #pragma unroll
      for (int i = 0; i < 8; ++i) {
        int word = tid + 512 * i;
        if (vv[i] != SENT) {
          int b = word >> 8, dp2 = word & 255;
          *(unsigned int*)((char*)h_lds + ((b * 1024 + dp2 * 4) ^ ((b & 7) << 4))) = vv[i];
        } else pend |= 1u << i;
      }
      while (pend) {
        __builtin_amdgcn_s_sleep(1);
        unsigned int np = pend;
        #pragma unroll
        for (int i = 0; i < 8; ++i) if (pend & (1u << i)) {
          unsigned int v = __hip_atomic_load(&src[tid + 512 * i], __ATOMIC_RELAXED,
                                             __HIP_MEMORY_SCOPE_AGENT);
          if (v != SENT) {
            int word = tid + 512 * i;
            int b = word >> 8, dp2 = word & 255;
            *(unsigned int*)((char*)h_lds + ((b * 1024 + dp2 * 4) ^ ((b & 7) << 4))) = v;
            np &= ~(1u << i);
          }
        }
        pend = np;
      }
    }
    __syncthreads();

    // ---- rec = h @ U_slice : waves 0..5, one 16-col tile each ----
    if (wave < 6) {
      float4v acc0 = {}, acc1 = {};
      #pragma unroll
      for (int kk = 0; kk < 16; ++kk) {
        int byteoff = (lr * 1024 + kk * 64 + lg * 16) ^ ((lr & 7) << 4);
        short8v a = *(const short8v*)((const char*)h_lds + byteoff);
        if (kk & 1) acc1 = __builtin_amdgcn_mfma_f32_16x16x32_bf16(a, Bf[kk], acc1, 0, 0, 0);
        else        acc0 = __builtin_amdgcn_mfma_f32_16x16x32_bf16(a, Bf[kk], acc0, 0, 0, 0);
      }
      // D: col = lane&15 (n), row = (lane>>4)*4 + r (batch)
      #pragma unroll
      for (int r = 0; r < 4; ++r)
        red[(lg * 4 + r) * 97 + wave * 16 + lr] = acc0[r] + acc1[r];
    }
    __syncthreads();

    // ---- gates: 256 threads, each owns (batch gb, dims 2dp, 2dp+1) ----
    if (tid < 256) {
      float rz0 = red[gb * 97 + 2 * dp],      rz1 = red[gb * 97 + 2 * dp + 1];
      float rr0 = red[gb * 97 + 32 + 2 * dp], rr1 = red[gb * 97 + 33 + 2 * dp];
      float rh0 = red[gb * 97 + 64 + 2 * dp], rh1 = red[gb * 97 + 65 + 2 * dp];
      float xz0 = bf2f((unsigned short)(xzw & 0xffff)), xz1 = bf2f((unsigned short)(xzw >> 16));
      float xr0 = bf2f((unsigned short)(xrw & 0xffff)), xr1 = bf2f((unsigned short)(xrw >> 16));
      float xh0 = bf2f((unsigned short)(xhw & 0xffff)), xh1 = bf2f((unsigned short)(xhw >> 16));
      float z0 = 1.f / (1.f + __expf(-(xz0 + rz0 + bz0)));
      float z1 = 1.f / (1.f + __expf(-(xz1 + rz1 + bz1)));
      float r0 = 1.f / (1.f + __expf(-(xr0 + rr0 + br0)));
      float r1 = 1.f / (1.f + __expf(-(xr1 + rr1 + br1)));
      float hh0 = tanhf(xh0 + r0 * (rh0 + bh0));
      float hh1 = tanhf(xh1 + r1 * (rh1 + bh1));
      h0 = z0 * h0 + (1.f - z0) * hh0;
      h1 = z1 * h1 + (1.f - z1) * hh1;
      unsigned int pack = (unsigned int)f2bf(h0) | ((unsigned int)f2bf(h1) << 16);
      __hip_atomic_store(&Hex[(size_t)(s + 1) * 4096 + gb * 256 + 16 * w + dp], pack,
                         __ATOMIC_RELAXED, __HIP_MEMORY_SCOPE_AGENT);
      ((unsigned int*)Hall)[(size_t)(gb * 256 + s) * 256 + 16 * w + dp] = pack;
    }
    __syncthreads();   // MFMA h_lds reads done before next step's poll overwrites
  }
}

// ---------------- launch ----------------
extern "C" void kernel_launch(void* const* d_in, const int* in_sizes, int n_in,
                              void* d_out, int out_size, void* d_ws, size_t ws_size,
                              hipStream_t stream) {
  const int*   x  = (const int*)d_in[0];
  const float* E  = (const float*)d_in[1];
  const float* W  = (const float*)d_in[2];
  const float* U  = (const float*)d_in[3];
  const float* bv = (const float*)d_in[4];
  const float* Wd = (const float*)d_in[5];
  const float* bd = (const float*)d_in[6];
  float* out = (float*)d_out;

  char* ws = (char*)d_ws;
  size_t off = 0;
  auto alloc = [&](size_t bytes) -> void* {
    void* p = ws + off;
    off = (off + bytes + 255) & ~(size_t)255;
    return p;
  };
  unsigned short* Aemb = (unsigned short*)alloc((size_t)NM * NE * 2);
  unsigned short* WT   = (unsigned short*)alloc((size_t)N3H * NE * 2);
  float*          UT   = (float*)alloc((size_t)N3H * NH * 4);
  unsigned short* xwb  = (unsigned short*)alloc((size_t)NM * N3H * 2);
  unsigned short* WdT  = (unsigned short*)alloc((size_t)NV * NH * 2);
  unsigned short* Hall = (unsigned short*)alloc((size_t)NM * NH * 2);
  unsigned int*   Hex  = (unsigned int*)alloc((size_t)257 * 4096 * 4);

  hipMemsetAsync(Hex, 0xFF, (size_t)257 * 4096 * 4, stream);

  gather_emb<<<NM / 4, 256, 0, stream>>>(x, E, Aemb);
  transpose_conv<unsigned short><<<dim3(N3H / 32, NE / 32), dim3(32, 8), 0, stream>>>(W,  WT,  NE, N3H);
  transpose_conv<unsigned short><<<dim3(NV / 32,  NH / 32), dim3(32, 8), 0, stream>>>(Wd, WdT, NH, NV);
  transpose_conv<float>         <<<dim3(N3H / 32, NH / 32), dim3(32, 8), 0, stream>>>(U,  UT,  NH, N3H);

  gemm_bt<true><<<dim3(N3H / 128, NM / 128), 256, 0, stream>>>(Aemb, WT, bv, xwb, N3H, NE);

  gru_kernel<<<16, 512, 0, stream>>>(xwb, UT, bv, Hall, Hex);

  gemm_bt<false><<<dim3(NV / 128, NM / 128), 256, 0, stream>>>(Hall, WdT, bd, out, NV, NH);
}

// Round 3
// 812.932 us; speedup vs baseline: 3.9303x; 1.4662x over previous
//
#include <hip/hip_runtime.h>
#include <hip/hip_bf16.h>
#include <stdint.h>
#include <stddef.h>

// ---------------- problem dims ----------------
#define NB 16
#define NS 256
#define NH 512
#define NE 256
#define NV 32000
#define NM (NB*NS)        // 4096 flattened rows, m = b*256 + s
#define N3H 1536

typedef __attribute__((ext_vector_type(8))) short short8v;
typedef __attribute__((ext_vector_type(4))) float float4v;
typedef __attribute__((address_space(1))) const unsigned int gas_u32;
typedef __attribute__((address_space(3))) unsigned int las_u32;

static __device__ __forceinline__ unsigned short f2bf(float f) {
  __hip_bfloat16 h = __float2bfloat16(f);
  return *reinterpret_cast<unsigned short*>(&h);
}
static __device__ __forceinline__ float bf2f(unsigned short u) {
  union { unsigned int u; float f; } c;
  c.u = ((unsigned int)u) << 16;
  return c.f;
}
static __device__ __forceinline__ float fast_tanh(float x) {
  float t = __expf(2.f * x);
  return (t - 1.f) / (t + 1.f);
}

// ---------------- embedding gather + convert to bf16 ----------------
__global__ void gather_emb(const int* __restrict__ x, const float* __restrict__ E,
                           unsigned short* __restrict__ A) {
  int m = blockIdx.x * 4 + (threadIdx.x >> 6);
  int lane = threadIdx.x & 63;
  int t = x[m];
  float4 v = reinterpret_cast<const float4*>(E + (size_t)t * NE)[lane];
  ushort4 o = make_ushort4(f2bf(v.x), f2bf(v.y), f2bf(v.z), f2bf(v.w));
  reinterpret_cast<ushort4*>(A + (size_t)m * NE)[lane] = o;
}

// ---------------- tiled transpose, f32 in -> (bf16|f32) out ----------------
template<typename T>
__global__ void transpose_conv(const float* __restrict__ in, T* __restrict__ out,
                               int R, int C) {
  __shared__ float tile[32][33];
  int c0 = blockIdx.x * 32, r0 = blockIdx.y * 32;
  int tx = threadIdx.x, ty = threadIdx.y;
  #pragma unroll
  for (int i = 0; i < 32; i += 8)
    tile[ty + i][tx] = in[(size_t)(r0 + ty + i) * C + (c0 + tx)];
  __syncthreads();
  #pragma unroll
  for (int i = 0; i < 32; i += 8) {
    float v = tile[tx][ty + i];
    if constexpr (sizeof(T) == 2)
      out[(size_t)(c0 + ty + i) * R + (r0 + tx)] = (T)f2bf(v);
    else
      out[(size_t)(c0 + ty + i) * R + (r0 + tx)] = (T)v;
  }
}

// ---------------- bf16 MFMA GEMM: C[m][n] = sum_k A[m][k]*BT[n][k] + bias[n]
// XCD-aware bijective block swizzle (m204).
template<bool OUT_BF16>
__launch_bounds__(256)
__global__ void gemm_bt(const unsigned short* __restrict__ A,
                        const unsigned short* __restrict__ BT,
                        const float* __restrict__ bias,
                        void* __restrict__ out, int N, int K) {
  __shared__ unsigned short As[128 * 32];
  __shared__ unsigned short Bs[128 * 32];
  const int tid = threadIdx.x;
  const int lane = tid & 63, wave = tid >> 6;
  const int wr = wave >> 1, wc = wave & 1;
  int nwg = gridDim.x * gridDim.y;
  int bid0 = blockIdx.y * gridDim.x + blockIdx.x;
  int q = nwg >> 3, r8 = nwg & 7;
  int xcd = bid0 & 7, idx = bid0 >> 3;
  int bid = (xcd < r8 ? xcd * (q + 1) : r8 * (q + 1) + (xcd - r8) * q) + idx;
  const int m0 = (bid / gridDim.x) * 128, n0 = (bid % gridDim.x) * 128;
  const int lr = lane & 15, lg = lane >> 4;
  float4v acc[4][4] = {};

  for (int k0 = 0; k0 < K; k0 += 32) {
    const char* Ab = (const char*)A;
    const char* Bb = (const char*)BT;
    #pragma unroll
    for (int qq = 0; qq < 2; ++qq) {
      int byteoff = qq * 4096 + tid * 16;
      int rr = byteoff >> 6, cb = byteoff & 63;
      const char* ga = Ab + ((size_t)(m0 + rr) * K + k0) * 2 + cb;
      const char* gb = Bb + ((size_t)(n0 + rr) * K + k0) * 2 + cb;
      char* la = (char*)As + qq * 4096 + wave * 1024;
      char* lb = (char*)Bs + qq * 4096 + wave * 1024;
      __builtin_amdgcn_global_load_lds((gas_u32*)ga, (las_u32*)la, 16, 0, 0);
      __builtin_amdgcn_global_load_lds((gas_u32*)gb, (las_u32*)lb, 16, 0, 0);
    }
    __syncthreads();
    short8v a[4], b[4];
    #pragma unroll
    for (int i = 0; i < 4; ++i)
      a[i] = *(const short8v*)((const char*)As + (wr * 64 + i * 16 + lr) * 64 + lg * 16);
    #pragma unroll
    for (int j = 0; j < 4; ++j)
      b[j] = *(const short8v*)((const char*)Bs + (wc * 64 + j * 16 + lr) * 64 + lg * 16);
    #pragma unroll
    for (int i = 0; i < 4; ++i) {
      #pragma unroll
      for (int j = 0; j < 4; ++j)
        acc[i][j] = __builtin_amdgcn_mfma_f32_16x16x32_bf16(a[i], b[j], acc[i][j], 0, 0, 0);
    }
    __syncthreads();
  }
  #pragma unroll
  for (int i = 0; i < 4; ++i) {
    int row = m0 + wr * 64 + i * 16 + lg * 4;
    #pragma unroll
    for (int j = 0; j < 4; ++j) {
      int col = n0 + wc * 64 + j * 16 + lr;
      float bv = bias[col];
      #pragma unroll
      for (int rr = 0; rr < 4; ++rr) {
        float v = acc[i][j][rr] + bv;
        if constexpr (OUT_BF16)
          ((unsigned short*)out)[(size_t)(row + rr) * N + col] = f2bf(v);
        else
          ((float*)out)[(size_t)(row + rr) * N + col] = v;
      }
    }
  }
}

// ---------------- persistent GRU, batch-partitioned data-as-flag exchange ----
// 64 WGs x 384 threads = 4 groups (4 batches each) x 16 WGs (32 h-dims each).
// U-slice (96 cols) lives in VGPRs. Per step, within a group only:
//   poll 1024 words of Hex[s][grp] (sentinel) -> h_lds  [own 64 words skipped]
//   -> sync -> 6 waves: rec = h(4x512) @ U_slice via mfma -> red
//   -> sync -> 64 gate threads: gates, h update, store Hex[s+1], own->LDS.
#define SENT 0xFFFFFFFFu
__launch_bounds__(384, 1)
__global__ void gru_kernel(const unsigned short* __restrict__ xw,   // [4096][1536] bf16
                           const float* __restrict__ UT,            // [1536][512] f32
                           const float* __restrict__ bvec,          // b[2][1536]
                           unsigned short* __restrict__ Hall,       // [4096][512] bf16
                           unsigned int* __restrict__ Hex) {        // [257][4][1024] words, memset 0xFF
  const int w = blockIdx.x, tid = threadIdx.x;
  const int grp = w >> 4;          // batches 4*grp .. 4*grp+3
  const int wq = w & 15;           // h-dims 32*wq .. 32*wq+32
  const int lane = tid & 63, wave = tid >> 6;
  const int lr = lane & 15, lg = lane >> 4;
  __shared__ unsigned short h_lds[4 * 512];    // 4KB, row = b_loc, XOR-swizzled
  __shared__ float red[4][100];                // rec staging

  // ---- one-time: U slice -> VGPR B-fragments (all 6 waves) ----
  int c = wave * 16 + lr;                      // 0..95
  int g = c >> 5, dloc = c & 31;
  const float* up = UT + (size_t)(g * 512 + 32 * wq + dloc) * 512 + lg * 8;
  short8v Bf[16];
  #pragma unroll
  for (int kk = 0; kk < 16; ++kk) {
    float4 v0 = *(const float4*)(up + kk * 32);
    float4 v1 = *(const float4*)(up + kk * 32 + 4);
    short8v t;
    t[0] = (short)f2bf(v0.x); t[1] = (short)f2bf(v0.y);
    t[2] = (short)f2bf(v0.z); t[3] = (short)f2bf(v0.w);
    t[4] = (short)f2bf(v1.x); t[5] = (short)f2bf(v1.y);
    t[6] = (short)f2bf(v1.z); t[7] = (short)f2bf(v1.w);
    Bf[kk] = t;
  }
  // zero h_lds (h0 = 0)
  for (int idx = tid; idx < 256; idx += 384)
    reinterpret_cast<uint4*>(h_lds)[idx] = make_uint4(0, 0, 0, 0);

  // ---- gate-thread constants (tid < 64): (b_loc, dim-pair dp) ----
  float h0 = 0.f, h1 = 0.f;
  float bz0 = 0, bz1 = 0, br0 = 0, br1 = 0, bh0 = 0, bh1 = 0;
  const int b_loc = tid >> 4, dp = tid & 15;
  const unsigned int* xp = nullptr;
  if (tid < 64) {
    const float* brec = bvec + 1536;
    int d = 32 * wq + 2 * dp;
    int b = grp * 4 + b_loc;
    bz0 = brec[d];        bz1 = brec[d + 1];
    br0 = brec[512 + d];  br1 = brec[513 + d];
    bh0 = brec[1024 + d]; bh1 = brec[1025 + d];
    xp = (const unsigned int*)xw + ((size_t)(b * 256) * 1536 + d) / 2;
  }
  // poll constants (tid < 256): 4 words, own-slice threads skip
  const int pb = tid >> 6;                       // b_loc of polled words
  const bool own = ((tid >> 2) & 15) == wq;
  __syncthreads();

  for (int s = 0; s < 256; ++s) {
    // prefetch xw for this step
    unsigned int xzw = 0, xrw = 0, xhw = 0;
    if (tid < 64) { xzw = xp[0]; xrw = xp[256]; xhw = xp[512]; xp += 768; }

    if (s > 0 && tid < 256 && !own) {
      const unsigned int* src = Hex + ((size_t)s * 4 + grp) * 1024 + tid * 4;
      unsigned int vv[4];
      #pragma unroll
      for (int i = 0; i < 4; ++i)
        vv[i] = __hip_atomic_load(&src[i], __ATOMIC_RELAXED, __HIP_MEMORY_SCOPE_AGENT);
      unsigned int pend = 0xF;
      while (pend) {
        unsigned int np = 0;
        #pragma unroll
        for (int i = 0; i < 4; ++i) if (pend & (1u << i)) {
          if (vv[i] != SENT) {
            int dpp = (tid & 63) * 4 + i;
            *(unsigned int*)((char*)h_lds + ((pb * 1024 + dpp * 4) ^ (pb << 4))) = vv[i];
          } else np |= 1u << i;
        }
        pend = np;
        if (pend) {
          __builtin_amdgcn_s_sleep(1);
          #pragma unroll
          for (int i = 0; i < 4; ++i) if (pend & (1u << i))
            vv[i] = __hip_atomic_load(&src[i], __ATOMIC_RELAXED, __HIP_MEMORY_SCOPE_AGENT);
        }
      }
    }
    __syncthreads();

    // ---- rec = h(4x512) @ U_slice : 6 waves, 16 cols each ----
    {
      float4v acc0 = {}, acc1 = {};
      #pragma unroll
      for (int kk = 0; kk < 16; ++kk) {
        int byteoff = ((lr & 3) * 1024 + kk * 64 + lg * 16) ^ ((lr & 3) << 4);
        short8v a = *(const short8v*)((const char*)h_lds + byteoff);
        if (kk & 1) acc1 = __builtin_amdgcn_mfma_f32_16x16x32_bf16(a, Bf[kk], acc1, 0, 0, 0);
        else        acc0 = __builtin_amdgcn_mfma_f32_16x16x32_bf16(a, Bf[kk], acc0, 0, 0, 0);
      }
      if (lg == 0) {     // rows 0..3 = batches (rows 4..15 are duplicates)
        #pragma unroll
        for (int rr = 0; rr < 4; ++rr)
          red[rr][c] = acc0[rr] + acc1[rr];
      }
    }
    __syncthreads();

    // ---- gates: 64 threads, each owns (b_loc, dims 2dp, 2dp+1) ----
    if (tid < 64) {
      float rz0 = red[b_loc][2 * dp],      rz1 = red[b_loc][2 * dp + 1];
      float rr0 = red[b_loc][32 + 2 * dp], rr1 = red[b_loc][33 + 2 * dp];
      float rh0 = red[b_loc][64 + 2 * dp], rh1 = red[b_loc][65 + 2 * dp];
      float xz0 = bf2f((unsigned short)(xzw & 0xffff)), xz1 = bf2f((unsigned short)(xzw >> 16));
      float xr0 = bf2f((unsigned short)(xrw & 0xffff)), xr1 = bf2f((unsigned short)(xrw >> 16));
      float xh0 = bf2f((unsigned short)(xhw & 0xffff)), xh1 = bf2f((unsigned short)(xhw >> 16));
      float z0 = 1.f / (1.f + __expf(-(xz0 + rz0 + bz0)));
      float z1 = 1.f / (1.f + __expf(-(xz1 + rz1 + bz1)));
      float r0 = 1.f / (1.f + __expf(-(xr0 + rr0 + br0)));
      float r1 = 1.f / (1.f + __expf(-(xr1 + rr1 + br1)));
      float hh0 = fast_tanh(xh0 + r0 * (rh0 + bh0));
      float hh1 = fast_tanh(xh1 + r1 * (rh1 + bh1));
      h0 = z0 * h0 + (1.f - z0) * hh0;
      h1 = z1 * h1 + (1.f - z1) * hh1;
      unsigned int pack = (unsigned int)f2bf(h0) | ((unsigned int)f2bf(h1) << 16);
      int dpp = wq * 16 + dp;
      // remote-visible store first (drains earliest)
      __hip_atomic_store(&Hex[((size_t)(s + 1) * 4 + grp) * 1024 + b_loc * 256 + dpp], pack,
                         __ATOMIC_RELAXED, __HIP_MEMORY_SCOPE_AGENT);
      // own slice straight into LDS for next step
      *(unsigned int*)((char*)h_lds + ((b_loc * 1024 + dpp * 4) ^ (b_loc << 4))) = pack;
      ((unsigned int*)Hall)[(size_t)((grp * 4 + b_loc) * 256 + s) * 256 + dpp] = pack;
    }
    // no third barrier: next-step poll/gate writes touch disjoint words, and
    // MFMA(s+1) reads h_lds only after the next __syncthreads().
  }
}

// ---------------- launch ----------------
extern "C" void kernel_launch(void* const* d_in, const int* in_sizes, int n_in,
                              void* d_out, int out_size, void* d_ws, size_t ws_size,
                              hipStream_t stream) {
  const int*   x  = (const int*)d_in[0];
  const float* E  = (const float*)d_in[1];
  const float* W  = (const float*)d_in[2];
  const float* U  = (const float*)d_in[3];
  const float* bv = (const float*)d_in[4];
  const float* Wd = (const float*)d_in[5];
  const float* bd = (const float*)d_in[6];
  float* out = (float*)d_out;

  char* ws = (char*)d_ws;
  size_t off = 0;
  auto alloc = [&](size_t bytes) -> void* {
    void* p = ws + off;
    off = (off + bytes + 255) & ~(size_t)255;
    return p;
  };
  unsigned short* Aemb = (unsigned short*)alloc((size_t)NM * NE * 2);
  unsigned short* WT   = (unsigned short*)alloc((size_t)N3H * NE * 2);
  float*          UT   = (float*)alloc((size_t)N3H * NH * 4);
  unsigned short* xwb  = (unsigned short*)alloc((size_t)NM * N3H * 2);
  unsigned short* WdT  = (unsigned short*)alloc((size_t)NV * NH * 2);
  unsigned short* Hall = (unsigned short*)alloc((size_t)NM * NH * 2);
  unsigned int*   Hex  = (unsigned int*)alloc((size_t)257 * 4096 * 4);

  hipMemsetAsync(Hex, 0xFF, (size_t)257 * 4096 * 4, stream);

  gather_emb<<<NM / 4, 256, 0, stream>>>(x, E, Aemb);
  transpose_conv<unsigned short><<<dim3(N3H / 32, NE / 32), dim3(32, 8), 0, stream>>>(W,  WT,  NE, N3H);
  transpose_conv<unsigned short><<<dim3(NV / 32,  NH / 32), dim3(32, 8), 0, stream>>>(Wd, WdT, NH, NV);
  transpose_conv<float>         <<<dim3(N3H / 32, NH / 32), dim3(32, 8), 0, stream>>>(U,  UT,  NH, N3H);

  gemm_bt<true><<<dim3(N3H / 128, NM / 128), 256, 0, stream>>>(Aemb, WT, bv, xwb, N3H, NE);

  gru_kernel<<<64, 384, 0, stream>>>(xwb, UT, bv, Hall, Hex);

  gemm_bt<false><<<dim3(NV / 128, NM / 128), 256, 0, stream>>>(Hall, WdT, bd, out, NV, NH);
}